// Round 6
// baseline (341.788 us; speedup 1.0000x reference)
//
#include <hip/hip_runtime.h>

#define NB 8
#define NN 2048
#define DIN 256
#define HID 64
#define JSPLIT 8

typedef __bf16 bf16x8_t __attribute__((ext_vector_type(8)));
typedef float f32x16_t __attribute__((ext_vector_type(16)));

// ---------------------------------------------------------------------------
// k1: Wh = x@W (fp32), f1 = Wh@a1, f2 = Wh@a2, and write WhT hi/lo bf16 split
// transposed to [b][h][n] so k3's LDS stage-in is coalesced.
// ---------------------------------------------------------------------------
__global__ __launch_bounds__(256) void k_wh(
    const float* __restrict__ x, const float* __restrict__ W,
    const float* __restrict__ a,
    __bf16* __restrict__ wht_hi, __bf16* __restrict__ wht_lo,
    float* __restrict__ f1, float* __restrict__ f2)
{
    __shared__ float smem[DIN * 64];   // 64 KB, reused later as T[h][row]
    const int t = threadIdx.x;
    const int g0 = blockIdx.x * 64;    // global row base (over B*N)
    const int b = g0 >> 11;
    const int n0 = g0 & (NN - 1);

    const float4* x4 = (const float4*)x;
#pragma unroll
    for (int it = 0; it < 16; ++it) {
        int c = t + it * 256;
        int row = c & 63;
        int dg = c >> 6;
        float4 v = x4[(size_t)(g0 + row) * 64 + dg];
        smem[(dg * 4 + 0) * 64 + row] = v.x;
        smem[(dg * 4 + 1) * 64 + row] = v.y;
        smem[(dg * 4 + 2) * 64 + row] = v.z;
        smem[(dg * 4 + 3) * 64 + row] = v.w;
    }
    __syncthreads();

    const int hq = t & 15;   // h-quad: cols hq*4..+3
    const int rg = t >> 4;   // row-group: rows rg*4..+3
    const float4* W4 = (const float4*)W;
    float acc[4][4] = {};
#pragma unroll 8
    for (int d = 0; d < DIN; ++d) {
        float4 wv = W4[d * 16 + hq];
        float4 xv = *(const float4*)&smem[d * 64 + rg * 4];
        float xr[4] = {xv.x, xv.y, xv.z, xv.w};
        float wk[4] = {wv.x, wv.y, wv.z, wv.w};
#pragma unroll
        for (int r = 0; r < 4; ++r)
#pragma unroll
            for (int k = 0; k < 4; ++k) acc[r][k] += xr[r] * wk[k];
    }

    // f1/f2: reduce over h (16 hq-lanes per row-group; xor<16 stays in group)
    float4 a1v = ((const float4*)a)[hq];
    float4 a2v = ((const float4*)a)[16 + hq];
#pragma unroll
    for (int r = 0; r < 4; ++r) {
        float p1 = acc[r][0] * a1v.x + acc[r][1] * a1v.y + acc[r][2] * a1v.z + acc[r][3] * a1v.w;
        float p2 = acc[r][0] * a2v.x + acc[r][1] * a2v.y + acc[r][2] * a2v.z + acc[r][3] * a2v.w;
#pragma unroll
        for (int m = 1; m < 16; m <<= 1) {
            p1 += __shfl_xor(p1, m);
            p2 += __shfl_xor(p2, m);
        }
        if (hq == 0) {
            f1[g0 + rg * 4 + r] = p1;
            f2[g0 + rg * 4 + r] = p2;
        }
    }

    __syncthreads();
    // transpose: T[h][row], 4-row groups XOR-swizzled to break bank conflicts
#pragma unroll
    for (int r = 0; r < 4; ++r)
#pragma unroll
        for (int k = 0; k < 4; ++k) {
            int h = hq * 4 + k;
            int row = rg * 4 + r;
            smem[h * 64 + (((row >> 2) ^ (h & 15)) << 2) + (row & 3)] = acc[r][k];
        }
    __syncthreads();

    const int h = t >> 2;    // 0..63
    const int rc = t & 3;    // 16-row chunk
    union { __bf16 bh[16]; uint4 u4[2]; } uh, ul;
#pragma unroll
    for (int q = 0; q < 4; ++q) {
        float4 v = *(const float4*)&smem[h * 64 + (((rc * 4 + q) ^ (h & 15)) << 2)];
        float vv[4] = {v.x, v.y, v.z, v.w};
#pragma unroll
        for (int e = 0; e < 4; ++e) {
            float val = vv[e];
            __bf16 hi = (__bf16)val;
            __bf16 lo = (__bf16)(val - (float)hi);
            uh.bh[q * 4 + e] = hi;
            ul.bh[q * 4 + e] = lo;
        }
    }
    size_t obase = (size_t)(b * HID + h) * NN + n0 + rc * 16;
    *(uint4*)&wht_hi[obase] = uh.u4[0];
    *(uint4*)&wht_hi[obase + 8] = uh.u4[1];
    *(uint4*)&wht_lo[obase] = ul.u4[0];
    *(uint4*)&wht_lo[obase + 8] = ul.u4[1];
}

// ---------------------------------------------------------------------------
// k2: f2max[b] = max_n f2[b][n]  (feeds the softmax shift bound)
// ---------------------------------------------------------------------------
__global__ __launch_bounds__(256) void k_f2max(
    const float* __restrict__ f2, float* __restrict__ f2mx)
{
    __shared__ float red[4];
    const int b = blockIdx.x, t = threadIdx.x;
    float m = -3.4e38f;
    for (int i = t; i < NN; i += 256) m = fmaxf(m, f2[b * NN + i]);
#pragma unroll
    for (int s = 1; s < 64; s <<= 1) m = fmaxf(m, __shfl_xor(m, s));
    if ((t & 63) == 0) red[t >> 6] = m;
    __syncthreads();
    if (t == 0) f2mx[b] = fmaxf(fmaxf(red[0], red[1]), fmaxf(red[2], red[3]));
}

// ---------------------------------------------------------------------------
// k3: fused adjacency-pack + masked-softmax + P@Wh (32x32x16 bf16 MFMA hi/lo),
// software-pipelined at 64-j chunk granularity. Per chunk:
//   (1) ballot-consume chunk c's 32 prefetched adj dwords (vmcnt wait covered
//       by chunk c-1's compute), freeing A[] for reuse;
//   (2) issue chunk c+1's adj (32 coalesced wave-loads) + WhT loads;
//   (3) compute chunk c from LDS buf[c&1];
//   (4) ds_write chunk c+1's WhT into buf[~c&1]; one barrier.
// Single A[32] buffer keeps VGPRs ~108 < 128 (4 blocks/CU, no spill).
// ---------------------------------------------------------------------------
__global__ __launch_bounds__(256, 4) void k_attn(
    const int* __restrict__ adj, const __bf16* __restrict__ wht_hi,
    const __bf16* __restrict__ wht_lo, const float* __restrict__ f1,
    const float* __restrict__ f2, const float* __restrict__ f2mx,
    float* __restrict__ accp, float* __restrict__ zp)
{
    __shared__ __bf16 whi[2][64 * 64];   // [buf][h][j64], groups XOR-swizzled
    __shared__ __bf16 wlo[2][64 * 64];
    const int t = threadIdx.x;
    const int w = t >> 6, lane = t & 63;
    const int bx = blockIdx.x;
    const int js = bx & 7;
    const int it = (bx >> 3) & 15;
    const int b = bx >> 7;
    const int I0 = it * 128 + w * 32;
    const int half = lane >> 5;
    const int m32 = lane & 31;
    const int row = I0 + m32;
    const int jb0 = js * 256;

    const float f1v = f1[b * NN + row];
    float Mi = f1v + f2mx[b];
    Mi = Mi > 0.f ? Mi : 0.2f * Mi;            // lrelu monotone -> valid bound
    const float LOG2E = 1.4426950408889634f;
    const float negMiL = -Mi * LOG2E;
    const float* f2p = f2 + b * NN;

    // staging index precompute (slots t and t+256; 512 uint4 slots per array)
    const int h0 = t >> 3, g0 = t & 7;
    const int h1 = (t + 256) >> 3, g1 = t & 7;  // (t+256)&7 == t&7
    const int dst0 = h0 * 64 + ((g0 ^ (h0 & 7)) << 3);
    const int dst1 = h1 * 64 + ((g1 ^ (h1 & 7)) << 3);
    // NOTE: jb0 folded in here (R5 bug was missing jb0 in the prologue load)
    const __bf16* hi_s0 = wht_hi + (size_t)(b * HID + h0) * NN + jb0 + g0 * 8;
    const __bf16* hi_s1 = wht_hi + (size_t)(b * HID + h1) * NN + jb0 + g1 * 8;
    const __bf16* lo_s0 = wht_lo + (size_t)(b * HID + h0) * NN + jb0 + g0 * 8;
    const __bf16* lo_s1 = wht_lo + (size_t)(b * HID + h1) * NN + jb0 + g1 * 8;

    const int* adjbase = adj + ((size_t)b * NN + I0) * NN + jb0;

    f32x16_t acc0, acc1;
#pragma unroll
    for (int i = 0; i < 16; ++i) { acc0[i] = 0.f; acc1[i] = 0.f; }
    float zacc = 0.f;

    // ---- prologue: chunk-0 adj prefetch + chunk-0 WhT stage into buf0
    int A[32];
#pragma unroll
    for (int r = 0; r < 32; ++r) A[r] = adjbase[(size_t)r * NN + lane];
    {
        uint4 th0 = *(const uint4*)&hi_s0[0];
        uint4 th1 = *(const uint4*)&hi_s1[0];
        uint4 tl0 = *(const uint4*)&lo_s0[0];
        uint4 tl1 = *(const uint4*)&lo_s1[0];
        *(uint4*)&whi[0][dst0] = th0;
        *(uint4*)&whi[0][dst1] = th1;
        *(uint4*)&wlo[0][dst0] = tl0;
        *(uint4*)&wlo[0][dst1] = tl1;
    }
    __syncthreads();

#pragma unroll
    for (int c = 0; c < 4; ++c) {
        const int p = c & 1, np = p ^ 1;
        // (1) ballot-consume chunk c's adj (waits on loads issued last iter,
        //     whose latency was covered by last iter's compute); frees A[]
        uint64_t my = 0;
#pragma unroll
        for (int r = 0; r < 32; ++r) {
            unsigned long long bal = __ballot(A[r] != 0);
            if (m32 == r) my = bal;
        }
        // (2) issue chunk c+1's prefetches (in flight during compute below)
        uint4 th0, th1, tl0, tl1;
        if (c < 3) {
            const int jn = (c + 1) * 64;
#pragma unroll
            for (int r = 0; r < 32; ++r)
                A[r] = adjbase[(size_t)r * NN + jn + lane];
            th0 = *(const uint4*)&hi_s0[jn];
            th1 = *(const uint4*)&hi_s1[jn];
            tl0 = *(const uint4*)&lo_s0[jn];
            tl1 = *(const uint4*)&lo_s1[jn];
        }
        // (3) compute chunk c (64 j = 4 mfma-groups) from buf[p]
        const int jt = jb0 + c * 64;
#pragma unroll
        for (int s8 = 0; s8 < 4; ++s8) {
            const int jl = jt + s8 * 16 + half * 8;   // this lane's 8-j group
            const uint32_t bits8 = (uint32_t)(my >> (s8 * 16 + half * 8)) & 0xffu;
            float4 fa = *(const float4*)&f2p[jl];
            float4 fb = *(const float4*)&f2p[jl + 4];
            float fv[8] = {fa.x, fa.y, fa.z, fa.w, fb.x, fb.y, fb.z, fb.w};
            bf16x8_t ahi, alo;
#pragma unroll
            for (int jj = 0; jj < 8; ++jj) {
                float t1 = f1v + fv[jj];
                t1 = fmaxf(t1, 0.2f * t1);
                float pv = (bits8 & (1u << jj))
                         ? __builtin_amdgcn_exp2f(fmaf(t1, LOG2E, negMiL))
                         : 0.f;
                zacc += pv;
                __bf16 hb = (__bf16)pv;
                ahi[jj] = hb;
                alo[jj] = (__bf16)(pv - (float)hb);
            }
            const int gx = (2 * s8 + half) ^ (m32 & 7);
            bf16x8_t bh0 = *(const bf16x8_t*)&whi[p][m32 * 64 + (gx << 3)];
            bf16x8_t bl0 = *(const bf16x8_t*)&wlo[p][m32 * 64 + (gx << 3)];
            bf16x8_t bh1 = *(const bf16x8_t*)&whi[p][(m32 + 32) * 64 + (gx << 3)];
            bf16x8_t bl1 = *(const bf16x8_t*)&wlo[p][(m32 + 32) * 64 + (gx << 3)];
            acc0 = __builtin_amdgcn_mfma_f32_32x32x16_bf16(ahi, bh0, acc0, 0, 0, 0);
            acc0 = __builtin_amdgcn_mfma_f32_32x32x16_bf16(ahi, bl0, acc0, 0, 0, 0);
            acc0 = __builtin_amdgcn_mfma_f32_32x32x16_bf16(alo, bh0, acc0, 0, 0, 0);
            acc1 = __builtin_amdgcn_mfma_f32_32x32x16_bf16(ahi, bh1, acc1, 0, 0, 0);
            acc1 = __builtin_amdgcn_mfma_f32_32x32x16_bf16(ahi, bl1, acc1, 0, 0, 0);
            acc1 = __builtin_amdgcn_mfma_f32_32x32x16_bf16(alo, bh1, acc1, 0, 0, 0);
        }
        // (4) stage chunk c+1's WhT into buf[np], then one barrier
        if (c < 3) {
            *(uint4*)&whi[np][dst0] = th0;
            *(uint4*)&whi[np][dst1] = th1;
            *(uint4*)&wlo[np][dst0] = tl0;
            *(uint4*)&wlo[np][dst1] = tl1;
            __syncthreads();
        }
    }

    float zrow = zacc + __shfl_xor(zacc, 32);
    if (lane < 32) zp[(size_t)(js * NB + b) * NN + row] = zrow;
    float* ap = accp + (size_t)(js * NB + b) * NN * HID;
#pragma unroll
    for (int r = 0; r < 16; ++r) {
        int rr = (r & 3) + 8 * (r >> 2) + 4 * half;   // verified C-layout (m74/m101)
        ap[(size_t)(I0 + rr) * HID + m32] = acc0[r];
        ap[(size_t)(I0 + rr) * HID + m32 + 32] = acc1[r];
    }
}

// ---------------------------------------------------------------------------
// k4: out = (sum_js acc_js) / (sum_js Z_js)
// ---------------------------------------------------------------------------
__global__ __launch_bounds__(256) void k_combine(
    const float* __restrict__ accp, const float* __restrict__ zp,
    float* __restrict__ out)
{
    int gid = blockIdx.x * 256 + threadIdx.x;   // 0..262143 (float4 granules)
    int h4 = gid & 15;
    int rowg = gid >> 4;                        // b*N + n
    float z = 0.f;
    float sx = 0.f, sy = 0.f, sz = 0.f, sw = 0.f;
#pragma unroll
    for (int js = 0; js < JSPLIT; ++js) {
        size_t base = (size_t)js * NB * NN;
        z += zp[base + rowg];
        float4 v = ((const float4*)accp)[(base + rowg) * 16 + h4];
        sx += v.x; sy += v.y; sz += v.z; sw += v.w;
    }
    float zi = 1.f / z;
    float4 o = {sx * zi, sy * zi, sz * zi, sw * zi};
    ((float4*)out)[gid] = o;
}

extern "C" void kernel_launch(void* const* d_in, const int* in_sizes, int n_in,
                              void* d_out, int out_size, void* d_ws, size_t ws_size,
                              hipStream_t stream)
{
    const float* x = (const float*)d_in[0];
    const int* adj = (const int*)d_in[1];
    const float* W = (const float*)d_in[2];
    const float* a = (const float*)d_in[3];
    float* out = (float*)d_out;
    char* ws = (char*)d_ws;

    __bf16* wht_hi = (__bf16*)(ws);                          // 2 MB
    __bf16* wht_lo = (__bf16*)(ws + (2u << 20));             // 2 MB
    float* f1   = (float*)(ws + (4u << 20));                 // 64 KB
    float* f2   = (float*)(ws + (4u << 20) + (64u << 10));   // 64 KB
    float* f2mx = (float*)(ws + (4u << 20) + (128u << 10));  // 32 B
    float* accp = (float*)(ws + (5u << 20));                 // 32 MB (8 splits)
    float* zp   = (float*)(ws + (37u << 20));                // 512 KB

    hipLaunchKernelGGL(k_wh, dim3(256), dim3(256), 0, stream, x, W, a, wht_hi, wht_lo, f1, f2);
    hipLaunchKernelGGL(k_f2max, dim3(NB), dim3(256), 0, stream, f2, f2mx);
    hipLaunchKernelGGL(k_attn, dim3(1024), dim3(256), 0, stream, adj, wht_hi, wht_lo, f1, f2, f2mx, accp, zp);
    hipLaunchKernelGGL(k_combine, dim3(1024), dim3(256), 0, stream, accp, zp, out);
}

// Round 7
// 260.284 us; speedup vs baseline: 1.3131x; 1.3131x over previous
//
#include <hip/hip_runtime.h>

#define NB 8
#define NN 2048
#define DIN 256
#define HID 64
#define JSPLIT 8

typedef _Float16 f16x8_t __attribute__((ext_vector_type(8)));
typedef float f32x16_t __attribute__((ext_vector_type(16)));

// ---------------------------------------------------------------------------
// k1: Wh = x@W (fp32), f1 = Wh@a1, f2 = Wh@a2; write WhT as fp16 (RNE)
// transposed to [b][h][n] so k3's LDS stage-in is coalesced.
// ---------------------------------------------------------------------------
__global__ __launch_bounds__(256) void k_wh(
    const float* __restrict__ x, const float* __restrict__ W,
    const float* __restrict__ a,
    _Float16* __restrict__ wht,
    float* __restrict__ f1, float* __restrict__ f2)
{
    __shared__ float smem[DIN * 64];   // 64 KB, reused later as T[h][row]
    const int t = threadIdx.x;
    const int g0 = blockIdx.x * 64;    // global row base (over B*N)
    const int b = g0 >> 11;
    const int n0 = g0 & (NN - 1);

    const float4* x4 = (const float4*)x;
#pragma unroll
    for (int it = 0; it < 16; ++it) {
        int c = t + it * 256;
        int row = c & 63;
        int dg = c >> 6;
        float4 v = x4[(size_t)(g0 + row) * 64 + dg];
        smem[(dg * 4 + 0) * 64 + row] = v.x;
        smem[(dg * 4 + 1) * 64 + row] = v.y;
        smem[(dg * 4 + 2) * 64 + row] = v.z;
        smem[(dg * 4 + 3) * 64 + row] = v.w;
    }
    __syncthreads();

    const int hq = t & 15;   // h-quad: cols hq*4..+3
    const int rg = t >> 4;   // row-group: rows rg*4..+3
    const float4* W4 = (const float4*)W;
    float acc[4][4] = {};
#pragma unroll 8
    for (int d = 0; d < DIN; ++d) {
        float4 wv = W4[d * 16 + hq];
        float4 xv = *(const float4*)&smem[d * 64 + rg * 4];
        float xr[4] = {xv.x, xv.y, xv.z, xv.w};
        float wk[4] = {wv.x, wv.y, wv.z, wv.w};
#pragma unroll
        for (int r = 0; r < 4; ++r)
#pragma unroll
            for (int k = 0; k < 4; ++k) acc[r][k] += xr[r] * wk[k];
    }

    // f1/f2: reduce over h (16 hq-lanes per row-group; xor<16 stays in group)
    float4 a1v = ((const float4*)a)[hq];
    float4 a2v = ((const float4*)a)[16 + hq];
#pragma unroll
    for (int r = 0; r < 4; ++r) {
        float p1 = acc[r][0] * a1v.x + acc[r][1] * a1v.y + acc[r][2] * a1v.z + acc[r][3] * a1v.w;
        float p2 = acc[r][0] * a2v.x + acc[r][1] * a2v.y + acc[r][2] * a2v.z + acc[r][3] * a2v.w;
#pragma unroll
        for (int m = 1; m < 16; m <<= 1) {
            p1 += __shfl_xor(p1, m);
            p2 += __shfl_xor(p2, m);
        }
        if (hq == 0) {
            f1[g0 + rg * 4 + r] = p1;
            f2[g0 + rg * 4 + r] = p2;
        }
    }

    __syncthreads();
    // transpose: T[h][row], 4-row groups XOR-swizzled to break bank conflicts
#pragma unroll
    for (int r = 0; r < 4; ++r)
#pragma unroll
        for (int k = 0; k < 4; ++k) {
            int h = hq * 4 + k;
            int row = rg * 4 + r;
            smem[h * 64 + (((row >> 2) ^ (h & 15)) << 2) + (row & 3)] = acc[r][k];
        }
    __syncthreads();

    const int h = t >> 2;    // 0..63
    const int rc = t & 3;    // 16-row chunk
    union { _Float16 fh[16]; uint4 u4[2]; } uh;
#pragma unroll
    for (int q = 0; q < 4; ++q) {
        float4 v = *(const float4*)&smem[h * 64 + (((rc * 4 + q) ^ (h & 15)) << 2)];
        uh.fh[q * 4 + 0] = (_Float16)v.x;
        uh.fh[q * 4 + 1] = (_Float16)v.y;
        uh.fh[q * 4 + 2] = (_Float16)v.z;
        uh.fh[q * 4 + 3] = (_Float16)v.w;
    }
    size_t obase = (size_t)(b * HID + h) * NN + n0 + rc * 16;
    *(uint4*)&wht[obase] = uh.u4[0];
    *(uint4*)&wht[obase + 8] = uh.u4[1];
}

// ---------------------------------------------------------------------------
// k2: f2max[b] = max_n f2[b][n]  (feeds the softmax shift bound)
// ---------------------------------------------------------------------------
__global__ __launch_bounds__(256) void k_f2max(
    const float* __restrict__ f2, float* __restrict__ f2mx)
{
    __shared__ float red[4];
    const int b = blockIdx.x, t = threadIdx.x;
    float m = -3.4e38f;
    for (int i = t; i < NN; i += 256) m = fmaxf(m, f2[b * NN + i]);
#pragma unroll
    for (int s = 1; s < 64; s <<= 1) m = fmaxf(m, __shfl_xor(m, s));
    if ((t & 63) == 0) red[t >> 6] = m;
    __syncthreads();
    if (t == 0) f2mx[b] = fmaxf(fmaxf(red[0], red[1]), fmaxf(red[2], red[3]));
}

// ---------------------------------------------------------------------------
// k_pack: adjacency -> bitmask. One wave per row (2 rows/wave), 32 coalesced
// 256B loads + ballots per row; lane l<32 ends up holding word l -> one
// coalesced 256B store per row. Pure streaming, full occupancy, no LDS.
// maskbuf layout: uint64 [b*NN+row][32 words].
// ---------------------------------------------------------------------------
__global__ __launch_bounds__(256) void k_pack(
    const int* __restrict__ adj, unsigned long long* __restrict__ mb)
{
    const int t = threadIdx.x;
    const int lane = t & 63;
    const int wave = blockIdx.x * 4 + (t >> 6);   // 0..8191
#pragma unroll
    for (int rr = 0; rr < 2; ++rr) {
        const int row = wave * 2 + rr;            // 0..16383 (= b*NN+n)
        const int* ar = adj + (size_t)row * NN;
        unsigned long long myw = 0;
#pragma unroll
        for (int k = 0; k < 32; ++k) {
            unsigned long long bal = __ballot(ar[k * 64 + lane] != 0);
            if ((lane & 31) == k) myw = bal;
        }
        if (lane < 32) mb[(size_t)row * 32 + lane] = myw;
    }
}

// ---------------------------------------------------------------------------
// k3: masked-softmax + P@Wh via single fp16 32x32x16 MFMA.
// Mask comes prepacked (32B/lane, 2 loads); Wh staged to LDS (16 KB,
// XOR-swizzled, coalesced); f2 loads wave-broadcast. Z computed from the
// fp16-quantized p so numerator/denominator weights stay consistent.
// Softmax shift = per-row upper bound M_i = lrelu(f1_i + max f2):
// single pass, no rescale. JSPLIT=8 -> 1024 blocks, partials in k4.
// ---------------------------------------------------------------------------
__global__ __launch_bounds__(256, 4) void k_attn(
    const unsigned long long* __restrict__ mb, const _Float16* __restrict__ wht,
    const float* __restrict__ f1, const float* __restrict__ f2,
    const float* __restrict__ f2mx,
    float* __restrict__ accp, float* __restrict__ zp)
{
    __shared__ _Float16 whx[64 * 128];   // [h][j128], 8-elem groups XOR-swizzled
    const int t = threadIdx.x;
    const int w = t >> 6, lane = t & 63;
    const int bx = blockIdx.x;
    const int js = bx & 7;
    const int it = (bx >> 3) & 15;
    const int b = bx >> 7;
    const int I0 = it * 128 + w * 32;
    const int half = lane >> 5;
    const int m32 = lane & 31;
    const int row = I0 + m32;
    const int jb0 = js * 256;

    const float f1v = f1[b * NN + row];
    float Mi = f1v + f2mx[b];
    Mi = Mi > 0.f ? Mi : 0.2f * Mi;            // lrelu monotone -> valid bound
    const float LOG2E = 1.4426950408889634f;
    const float negMiL = -Mi * LOG2E;
    const float* f2p = f2 + b * NN;

    // this row's 4 mask words (j in [jb0, jb0+256))
    const unsigned long long* mrow = mb + (size_t)(b * NN + row) * 32 + js * 4;
    unsigned long long m[4];
    {
        ulonglong2 q0 = *(const ulonglong2*)mrow;
        ulonglong2 q1 = *(const ulonglong2*)(mrow + 2);
        m[0] = q0.x; m[1] = q0.y; m[2] = q1.x; m[3] = q1.y;
    }

    f32x16_t acc0, acc1;
#pragma unroll
    for (int i = 0; i < 16; ++i) { acc0[i] = 0.f; acc1[i] = 0.f; }
    float zacc = 0.f;

#pragma unroll
    for (int stg = 0; stg < 2; ++stg) {
        const int jt = jb0 + stg * 128;
        if (stg) __syncthreads();
#pragma unroll
        for (int cc = 0; cc < 4; ++cc) {
            int c = t + cc * 256;
            int h = c >> 4, g = c & 15;
            int gp = g ^ (h & 15);
            size_t src = (size_t)(b * HID + h) * NN + jt + g * 8;
            *(uint4*)&whx[h * 128 + gp * 8] = *(const uint4*)&wht[src];
        }
        __syncthreads();
#pragma unroll
        for (int s8 = 0; s8 < 8; ++s8) {
            const int jl = jt + s8 * 16 + half * 8;   // this lane's 8-j group
            const uint32_t bits8 =
                (uint32_t)(m[stg * 2 + (s8 >> 2)] >> (((s8 & 3) * 16) + half * 8)) & 0xffu;
            float4 fa = *(const float4*)&f2p[jl];
            float4 fb = *(const float4*)&f2p[jl + 4];
            float fv[8] = {fa.x, fa.y, fa.z, fa.w, fb.x, fb.y, fb.z, fb.w};
            f16x8_t ah;
#pragma unroll
            for (int jj = 0; jj < 8; ++jj) {
                float t1 = f1v + fv[jj];
                t1 = fmaxf(t1, 0.2f * t1);
                float pv = (bits8 & (1u << jj))
                         ? __builtin_amdgcn_exp2f(fmaf(t1, LOG2E, negMiL))
                         : 0.f;
                _Float16 ph = (_Float16)pv;
                ah[jj] = ph;
                zacc += (float)ph;       // Z from quantized p (consistency)
            }
            const int gx = (2 * s8 + half) ^ (m32 & 15);
            f16x8_t b0 = *(const f16x8_t*)&whx[m32 * 128 + (gx << 3)];
            f16x8_t b1 = *(const f16x8_t*)&whx[(m32 + 32) * 128 + (gx << 3)];
            acc0 = __builtin_amdgcn_mfma_f32_32x32x16_f16(ah, b0, acc0, 0, 0, 0);
            acc1 = __builtin_amdgcn_mfma_f32_32x32x16_f16(ah, b1, acc1, 0, 0, 0);
        }
    }

    float zrow = zacc + __shfl_xor(zacc, 32);
    if (lane < 32) zp[(size_t)(js * NB + b) * NN + row] = zrow;
    float* ap = accp + (size_t)(js * NB + b) * NN * HID;
#pragma unroll
    for (int r = 0; r < 16; ++r) {
        int rr = (r & 3) + 8 * (r >> 2) + 4 * half;   // verified C-layout (m74/m101)
        ap[(size_t)(I0 + rr) * HID + m32] = acc0[r];
        ap[(size_t)(I0 + rr) * HID + m32 + 32] = acc1[r];
    }
}

// ---------------------------------------------------------------------------
// k4: out = (sum_js acc_js) / (sum_js Z_js)
// ---------------------------------------------------------------------------
__global__ __launch_bounds__(256) void k_combine(
    const float* __restrict__ accp, const float* __restrict__ zp,
    float* __restrict__ out)
{
    int gid = blockIdx.x * 256 + threadIdx.x;   // 0..262143 (float4 granules)
    int h4 = gid & 15;
    int rowg = gid >> 4;                        // b*N + n
    float z = 0.f;
    float sx = 0.f, sy = 0.f, sz = 0.f, sw = 0.f;
#pragma unroll
    for (int js = 0; js < JSPLIT; ++js) {
        size_t base = (size_t)js * NB * NN;
        z += zp[base + rowg];
        float4 v = ((const float4*)accp)[(base + rowg) * 16 + h4];
        sx += v.x; sy += v.y; sz += v.z; sw += v.w;
    }
    float zi = 1.f / z;
    float4 o = {sx * zi, sy * zi, sz * zi, sw * zi};
    ((float4*)out)[gid] = o;
}

extern "C" void kernel_launch(void* const* d_in, const int* in_sizes, int n_in,
                              void* d_out, int out_size, void* d_ws, size_t ws_size,
                              hipStream_t stream)
{
    const float* x = (const float*)d_in[0];
    const int* adj = (const int*)d_in[1];
    const float* W = (const float*)d_in[2];
    const float* a = (const float*)d_in[3];
    float* out = (float*)d_out;
    char* ws = (char*)d_ws;

    _Float16* wht = (_Float16*)(ws);                              // 2 MB
    float* f1   = (float*)(ws + (2u << 20));                      // 64 KB
    float* f2   = (float*)(ws + (2u << 20) + (64u << 10));        // 64 KB
    float* f2mx = (float*)(ws + (2u << 20) + (128u << 10));       // 32 B
    unsigned long long* mbuf = (unsigned long long*)(ws + (3u << 20)); // 4 MB
    float* accp = (float*)(ws + (8u << 20));                      // 32 MB
    float* zp   = (float*)(ws + (40u << 20));                     // 512 KB

    hipLaunchKernelGGL(k_pack, dim3(2048), dim3(256), 0, stream, adj, mbuf);
    hipLaunchKernelGGL(k_wh, dim3(256), dim3(256), 0, stream, x, W, a, wht, f1, f2);
    hipLaunchKernelGGL(k_f2max, dim3(NB), dim3(256), 0, stream, f2, f2mx);
    hipLaunchKernelGGL(k_attn, dim3(1024), dim3(256), 0, stream, mbuf, wht, f1, f2, f2mx, accp, zp);
    hipLaunchKernelGGL(k_combine, dim3(1024), dim3(256), 0, stream, accp, zp, out);
}

// Round 8
// 235.497 us; speedup vs baseline: 1.4513x; 1.1053x over previous
//
#include <hip/hip_runtime.h>

#define NB 8
#define NN 2048
#define DIN 256
#define HID 64
#define JSPLIT 8

typedef _Float16 f16x8_t __attribute__((ext_vector_type(8)));
typedef float f32x16_t __attribute__((ext_vector_type(16)));

// ---------------------------------------------------------------------------
// k_prep: fused (wh-role | pack-role) — independent work, one launch so the
// compute-ish wh blocks overlap the memory-bound adjacency pack stream.
//   blocks 0..255   : Wh = x@W fp32, f1/f2, WhT fp16 [b][h][n]  (wh-role)
//   blocks 256..2303: adjacency -> 64-bit masks via wave ballot (pack-role)
// wh-role first so it's dispatched at t=0 and hides under pack's HBM stream.
// ---------------------------------------------------------------------------
__global__ __launch_bounds__(256) void k_prep(
    const float* __restrict__ x, const float* __restrict__ W,
    const float* __restrict__ a, const int* __restrict__ adj,
    unsigned long long* __restrict__ mb, _Float16* __restrict__ wht,
    float* __restrict__ f1, float* __restrict__ f2)
{
    __shared__ float smem[DIN * 64];   // 64 KB (wh-role only; reused as T[h][row])
    const int bid = blockIdx.x;
    const int t = threadIdx.x;

    if (bid >= 256) {
        // ---------------- pack-role ----------------
        const int lane = t & 63;
        const int wave = (bid - 256) * 4 + (t >> 6);   // 0..8191
#pragma unroll
        for (int rr = 0; rr < 2; ++rr) {
            const int row = wave * 2 + rr;             // 0..16383 (= b*NN+n)
            const int* ar = adj + (size_t)row * NN;
            unsigned long long myw = 0;
#pragma unroll
            for (int k = 0; k < 32; ++k) {
                unsigned long long bal = __ballot(ar[k * 64 + lane] != 0);
                if ((lane & 31) == k) myw = bal;
            }
            if (lane < 32) mb[(size_t)row * 32 + lane] = myw;
        }
        return;
    }

    // ---------------- wh-role ----------------
    const int g0 = bid * 64;           // global row base (over B*N)
    const int b = g0 >> 11;
    const int n0 = g0 & (NN - 1);

    const float4* x4 = (const float4*)x;
#pragma unroll
    for (int it = 0; it < 16; ++it) {
        int c = t + it * 256;
        int row = c & 63;
        int dg = c >> 6;
        float4 v = x4[(size_t)(g0 + row) * 64 + dg];
        smem[(dg * 4 + 0) * 64 + row] = v.x;
        smem[(dg * 4 + 1) * 64 + row] = v.y;
        smem[(dg * 4 + 2) * 64 + row] = v.z;
        smem[(dg * 4 + 3) * 64 + row] = v.w;
    }
    __syncthreads();

    const int hq = t & 15;   // h-quad: cols hq*4..+3
    const int rg = t >> 4;   // row-group: rows rg*4..+3
    const float4* W4 = (const float4*)W;
    float acc[4][4] = {};
#pragma unroll 8
    for (int d = 0; d < DIN; ++d) {
        float4 wv = W4[d * 16 + hq];
        float4 xv = *(const float4*)&smem[d * 64 + rg * 4];
        float xr[4] = {xv.x, xv.y, xv.z, xv.w};
        float wk[4] = {wv.x, wv.y, wv.z, wv.w};
#pragma unroll
        for (int r = 0; r < 4; ++r)
#pragma unroll
            for (int k = 0; k < 4; ++k) acc[r][k] += xr[r] * wk[k];
    }

    // f1/f2: reduce over h (16 hq-lanes per row-group; xor<16 stays in group)
    float4 a1v = ((const float4*)a)[hq];
    float4 a2v = ((const float4*)a)[16 + hq];
#pragma unroll
    for (int r = 0; r < 4; ++r) {
        float p1 = acc[r][0] * a1v.x + acc[r][1] * a1v.y + acc[r][2] * a1v.z + acc[r][3] * a1v.w;
        float p2 = acc[r][0] * a2v.x + acc[r][1] * a2v.y + acc[r][2] * a2v.z + acc[r][3] * a2v.w;
#pragma unroll
        for (int m = 1; m < 16; m <<= 1) {
            p1 += __shfl_xor(p1, m);
            p2 += __shfl_xor(p2, m);
        }
        if (hq == 0) {
            f1[g0 + rg * 4 + r] = p1;
            f2[g0 + rg * 4 + r] = p2;
        }
    }

    __syncthreads();
    // transpose: T[h][row], 4-row groups XOR-swizzled to break bank conflicts
#pragma unroll
    for (int r = 0; r < 4; ++r)
#pragma unroll
        for (int k = 0; k < 4; ++k) {
            int h = hq * 4 + k;
            int row = rg * 4 + r;
            smem[h * 64 + (((row >> 2) ^ (h & 15)) << 2) + (row & 3)] = acc[r][k];
        }
    __syncthreads();

    const int h = t >> 2;    // 0..63
    const int rc = t & 3;    // 16-row chunk
    union { _Float16 fh[16]; uint4 u4[2]; } uh;
#pragma unroll
    for (int q = 0; q < 4; ++q) {
        float4 v = *(const float4*)&smem[h * 64 + (((rc * 4 + q) ^ (h & 15)) << 2)];
        uh.fh[q * 4 + 0] = (_Float16)v.x;
        uh.fh[q * 4 + 1] = (_Float16)v.y;
        uh.fh[q * 4 + 2] = (_Float16)v.z;
        uh.fh[q * 4 + 3] = (_Float16)v.w;
    }
    size_t obase = (size_t)(b * HID + h) * NN + n0 + rc * 16;
    *(uint4*)&wht[obase] = uh.u4[0];
    *(uint4*)&wht[obase + 8] = uh.u4[1];
}

// ---------------------------------------------------------------------------
// k2: f2max[b] = max_n f2[b][n]  (feeds the softmax shift bound)
// ---------------------------------------------------------------------------
__global__ __launch_bounds__(256) void k_f2max(
    const float* __restrict__ f2, float* __restrict__ f2mx)
{
    __shared__ float red[4];
    const int b = blockIdx.x, t = threadIdx.x;
    float m = -3.4e38f;
    for (int i = t; i < NN; i += 256) m = fmaxf(m, f2[b * NN + i]);
#pragma unroll
    for (int s = 1; s < 64; s <<= 1) m = fmaxf(m, __shfl_xor(m, s));
    if ((t & 63) == 0) red[t >> 6] = m;
    __syncthreads();
    if (t == 0) f2mx[b] = fmaxf(fmaxf(red[0], red[1]), fmaxf(red[2], red[3]));
}

// ---------------------------------------------------------------------------
// k3: masked-softmax + P@Wh via single fp16 32x32x16 MFMA.
// Mask prepacked (32B/row-slice, 2 loads); Wh staged to LDS (16 KB,
// XOR-swizzled, coalesced); f2 loads wave-broadcast. Z from the fp16-quantized
// p so numerator/denominator stay consistent. Softmax shift = per-row upper
// bound M_i = lrelu(f1_i + max f2): single pass, no rescale. JSPLIT=8.
// ---------------------------------------------------------------------------
__global__ __launch_bounds__(256, 4) void k_attn(
    const unsigned long long* __restrict__ mb, const _Float16* __restrict__ wht,
    const float* __restrict__ f1, const float* __restrict__ f2,
    const float* __restrict__ f2mx,
    float* __restrict__ accp, float* __restrict__ zp)
{
    __shared__ _Float16 whx[64 * 128];   // [h][j128], 8-elem groups XOR-swizzled
    const int t = threadIdx.x;
    const int w = t >> 6, lane = t & 63;
    const int bx = blockIdx.x;
    const int js = bx & 7;
    const int it = (bx >> 3) & 15;
    const int b = bx >> 7;
    const int I0 = it * 128 + w * 32;
    const int half = lane >> 5;
    const int m32 = lane & 31;
    const int row = I0 + m32;
    const int jb0 = js * 256;

    const float f1v = f1[b * NN + row];
    float Mi = f1v + f2mx[b];
    Mi = Mi > 0.f ? Mi : 0.2f * Mi;            // lrelu monotone -> valid bound
    const float LOG2E = 1.4426950408889634f;
    const float negMiL = -Mi * LOG2E;
    const float* f2p = f2 + b * NN;

    // this row's 4 mask words (j in [jb0, jb0+256))
    const unsigned long long* mrow = mb + (size_t)(b * NN + row) * 32 + js * 4;
    unsigned long long m[4];
    {
        ulonglong2 q0 = *(const ulonglong2*)mrow;
        ulonglong2 q1 = *(const ulonglong2*)(mrow + 2);
        m[0] = q0.x; m[1] = q0.y; m[2] = q1.x; m[3] = q1.y;
    }

    f32x16_t acc0, acc1;
#pragma unroll
    for (int i = 0; i < 16; ++i) { acc0[i] = 0.f; acc1[i] = 0.f; }
    float zacc = 0.f;

#pragma unroll
    for (int stg = 0; stg < 2; ++stg) {
        const int jt = jb0 + stg * 128;
        if (stg) __syncthreads();
#pragma unroll
        for (int cc = 0; cc < 4; ++cc) {
            int c = t + cc * 256;
            int h = c >> 4, g = c & 15;
            int gp = g ^ (h & 15);
            size_t src = (size_t)(b * HID + h) * NN + jt + g * 8;
            *(uint4*)&whx[h * 128 + gp * 8] = *(const uint4*)&wht[src];
        }
        __syncthreads();
#pragma unroll
        for (int s8 = 0; s8 < 8; ++s8) {
            const int jl = jt + s8 * 16 + half * 8;   // this lane's 8-j group
            const uint32_t bits8 =
                (uint32_t)(m[stg * 2 + (s8 >> 2)] >> (((s8 & 3) * 16) + half * 8)) & 0xffu;
            float4 fa = *(const float4*)&f2p[jl];
            float4 fb = *(const float4*)&f2p[jl + 4];
            float fv[8] = {fa.x, fa.y, fa.z, fa.w, fb.x, fb.y, fb.z, fb.w};
            f16x8_t ah;
#pragma unroll
            for (int jj = 0; jj < 8; ++jj) {
                float t1 = f1v + fv[jj];
                t1 = fmaxf(t1, 0.2f * t1);
                float pv = (bits8 & (1u << jj))
                         ? __builtin_amdgcn_exp2f(fmaf(t1, LOG2E, negMiL))
                         : 0.f;
                _Float16 ph = (_Float16)pv;
                ah[jj] = ph;
                zacc += (float)ph;       // Z from quantized p (consistency)
            }
            const int gx = (2 * s8 + half) ^ (m32 & 15);
            f16x8_t b0 = *(const f16x8_t*)&whx[m32 * 128 + (gx << 3)];
            f16x8_t b1 = *(const f16x8_t*)&whx[(m32 + 32) * 128 + (gx << 3)];
            acc0 = __builtin_amdgcn_mfma_f32_32x32x16_f16(ah, b0, acc0, 0, 0, 0);
            acc1 = __builtin_amdgcn_mfma_f32_32x32x16_f16(ah, b1, acc1, 0, 0, 0);
        }
    }

    float zrow = zacc + __shfl_xor(zacc, 32);
    if (lane < 32) zp[(size_t)(js * NB + b) * NN + row] = zrow;
    float* ap = accp + (size_t)(js * NB + b) * NN * HID;
#pragma unroll
    for (int r = 0; r < 16; ++r) {
        int rr = (r & 3) + 8 * (r >> 2) + 4 * half;   // verified C-layout (m74/m101)
        ap[(size_t)(I0 + rr) * HID + m32] = acc0[r];
        ap[(size_t)(I0 + rr) * HID + m32 + 32] = acc1[r];
    }
}

// ---------------------------------------------------------------------------
// k4: out = (sum_js acc_js) / (sum_js Z_js)
// ---------------------------------------------------------------------------
__global__ __launch_bounds__(256) void k_combine(
    const float* __restrict__ accp, const float* __restrict__ zp,
    float* __restrict__ out)
{
    int gid = blockIdx.x * 256 + threadIdx.x;   // 0..262143 (float4 granules)
    int h4 = gid & 15;
    int rowg = gid >> 4;                        // b*N + n
    float z = 0.f;
    float sx = 0.f, sy = 0.f, sz = 0.f, sw = 0.f;
#pragma unroll
    for (int js = 0; js < JSPLIT; ++js) {
        size_t base = (size_t)js * NB * NN;
        z += zp[base + rowg];
        float4 v = ((const float4*)accp)[(base + rowg) * 16 + h4];
        sx += v.x; sy += v.y; sz += v.z; sw += v.w;
    }
    float zi = 1.f / z;
    float4 o = {sx * zi, sy * zi, sz * zi, sw * zi};
    ((float4*)out)[gid] = o;
}

extern "C" void kernel_launch(void* const* d_in, const int* in_sizes, int n_in,
                              void* d_out, int out_size, void* d_ws, size_t ws_size,
                              hipStream_t stream)
{
    const float* x = (const float*)d_in[0];
    const int* adj = (const int*)d_in[1];
    const float* W = (const float*)d_in[2];
    const float* a = (const float*)d_in[3];
    float* out = (float*)d_out;
    char* ws = (char*)d_ws;

    _Float16* wht = (_Float16*)(ws);                              // 2 MB
    float* f1   = (float*)(ws + (2u << 20));                      // 64 KB
    float* f2   = (float*)(ws + (2u << 20) + (64u << 10));        // 64 KB
    float* f2mx = (float*)(ws + (2u << 20) + (128u << 10));       // 32 B
    unsigned long long* mbuf = (unsigned long long*)(ws + (3u << 20)); // 4 MB
    float* accp = (float*)(ws + (8u << 20));                      // 32 MB
    float* zp   = (float*)(ws + (40u << 20));                     // 512 KB

    hipLaunchKernelGGL(k_prep, dim3(2304), dim3(256), 0, stream,
                       x, W, a, adj, mbuf, wht, f1, f2);
    hipLaunchKernelGGL(k_f2max, dim3(NB), dim3(256), 0, stream, f2, f2mx);
    hipLaunchKernelGGL(k_attn, dim3(1024), dim3(256), 0, stream, mbuf, wht, f1, f2, f2mx, accp, zp);
    hipLaunchKernelGGL(k_combine, dim3(1024), dim3(256), 0, stream, accp, zp, out);
}

// Round 10
// 227.124 us; speedup vs baseline: 1.5049x; 1.0369x over previous
//
#include <hip/hip_runtime.h>

#define NB 8
#define NN 2048
#define DIN 256
#define HID 64
#define JSPLIT 8

typedef _Float16 f16x8_t __attribute__((ext_vector_type(8)));
typedef _Float16 f16x2_t __attribute__((ext_vector_type(2)));
typedef _Float16 f16x4_t __attribute__((ext_vector_type(4)));
typedef float f32x16_t __attribute__((ext_vector_type(16)));

// ---------------------------------------------------------------------------
// k_prep: fused (wh-role | pack-role) — independent work, one launch so the
// compute-ish wh blocks overlap the memory-bound adjacency pack stream.
//   blocks 0..255   : Wh = x@W fp32, f1/f2, WhT fp16 [b][h][n]  (wh-role)
//   blocks 256..2303: adjacency -> 64-bit masks via wave ballot (pack-role)
// ---------------------------------------------------------------------------
__global__ __launch_bounds__(256) void k_prep(
    const float* __restrict__ x, const float* __restrict__ W,
    const float* __restrict__ a, const int* __restrict__ adj,
    unsigned long long* __restrict__ mb, _Float16* __restrict__ wht,
    float* __restrict__ f1, float* __restrict__ f2)
{
    __shared__ float smem[DIN * 64];   // 64 KB (wh-role only; reused as T[h][row])
    const int bid = blockIdx.x;
    const int t = threadIdx.x;

    if (bid >= 256) {
        // ---------------- pack-role ----------------
        const int lane = t & 63;
        const int wave = (bid - 256) * 4 + (t >> 6);   // 0..8191
#pragma unroll
        for (int rr = 0; rr < 2; ++rr) {
            const int row = wave * 2 + rr;             // 0..16383 (= b*NN+n)
            const int* ar = adj + (size_t)row * NN;
            unsigned long long myw = 0;
#pragma unroll
            for (int k = 0; k < 32; ++k) {
                unsigned long long bal = __ballot(ar[k * 64 + lane] != 0);
                if ((lane & 31) == k) myw = bal;
            }
            if (lane < 32) mb[(size_t)row * 32 + lane] = myw;
        }
        return;
    }

    // ---------------- wh-role ----------------
    const int g0 = bid * 64;           // global row base (over B*N)
    const int b = g0 >> 11;
    const int n0 = g0 & (NN - 1);

    const float4* x4 = (const float4*)x;
#pragma unroll
    for (int it = 0; it < 16; ++it) {
        int c = t + it * 256;
        int row = c & 63;
        int dg = c >> 6;
        float4 v = x4[(size_t)(g0 + row) * 64 + dg];
        smem[(dg * 4 + 0) * 64 + row] = v.x;
        smem[(dg * 4 + 1) * 64 + row] = v.y;
        smem[(dg * 4 + 2) * 64 + row] = v.z;
        smem[(dg * 4 + 3) * 64 + row] = v.w;
    }
    __syncthreads();

    const int hq = t & 15;   // h-quad: cols hq*4..+3
    const int rg = t >> 4;   // row-group: rows rg*4..+3
    const float4* W4 = (const float4*)W;
    float acc[4][4] = {};
#pragma unroll 8
    for (int d = 0; d < DIN; ++d) {
        float4 wv = W4[d * 16 + hq];
        float4 xv = *(const float4*)&smem[d * 64 + rg * 4];
        float xr[4] = {xv.x, xv.y, xv.z, xv.w};
        float wk[4] = {wv.x, wv.y, wv.z, wv.w};
#pragma unroll
        for (int r = 0; r < 4; ++r)
#pragma unroll
            for (int k = 0; k < 4; ++k) acc[r][k] += xr[r] * wk[k];
    }

    // f1/f2: reduce over h (16 hq-lanes per row-group; xor<16 stays in group)
    float4 a1v = ((const float4*)a)[hq];
    float4 a2v = ((const float4*)a)[16 + hq];
#pragma unroll
    for (int r = 0; r < 4; ++r) {
        float p1 = acc[r][0] * a1v.x + acc[r][1] * a1v.y + acc[r][2] * a1v.z + acc[r][3] * a1v.w;
        float p2 = acc[r][0] * a2v.x + acc[r][1] * a2v.y + acc[r][2] * a2v.z + acc[r][3] * a2v.w;
#pragma unroll
        for (int m = 1; m < 16; m <<= 1) {
            p1 += __shfl_xor(p1, m);
            p2 += __shfl_xor(p2, m);
        }
        if (hq == 0) {
            f1[g0 + rg * 4 + r] = p1;
            f2[g0 + rg * 4 + r] = p2;
        }
    }

    __syncthreads();
    // transpose: T[h][row], 4-row groups XOR-swizzled to break bank conflicts
#pragma unroll
    for (int r = 0; r < 4; ++r)
#pragma unroll
        for (int k = 0; k < 4; ++k) {
            int h = hq * 4 + k;
            int row = rg * 4 + r;
            smem[h * 64 + (((row >> 2) ^ (h & 15)) << 2) + (row & 3)] = acc[r][k];
        }
    __syncthreads();

    const int h = t >> 2;    // 0..63
    const int rc = t & 3;    // 16-row chunk
    union { _Float16 fh[16]; uint4 u4[2]; } uh;
#pragma unroll
    for (int q = 0; q < 4; ++q) {
        float4 v = *(const float4*)&smem[h * 64 + (((rc * 4 + q) ^ (h & 15)) << 2)];
        uh.fh[q * 4 + 0] = (_Float16)v.x;
        uh.fh[q * 4 + 1] = (_Float16)v.y;
        uh.fh[q * 4 + 2] = (_Float16)v.z;
        uh.fh[q * 4 + 3] = (_Float16)v.w;
    }
    size_t obase = (size_t)(b * HID + h) * NN + n0 + rc * 16;
    *(uint4*)&wht[obase] = uh.u4[0];
    *(uint4*)&wht[obase + 8] = uh.u4[1];
}

// ---------------------------------------------------------------------------
// k2: f2max[b] = max_n f2[b][n]  (feeds the softmax shift bound)
// ---------------------------------------------------------------------------
__global__ __launch_bounds__(256) void k_f2max(
    const float* __restrict__ f2, float* __restrict__ f2mx)
{
    __shared__ float red[4];
    const int b = blockIdx.x, t = threadIdx.x;
    float m = -3.4e38f;
    for (int i = t; i < NN; i += 256) m = fmaxf(m, f2[b * NN + i]);
#pragma unroll
    for (int s = 1; s < 64; s <<= 1) m = fmaxf(m, __shfl_xor(m, s));
    if ((t & 63) == 0) red[t >> 6] = m;
    __syncthreads();
    if (t == 0) f2mx[b] = fmaxf(fmaxf(red[0], red[1]), fmaxf(red[2], red[3]));
}

// ---------------------------------------------------------------------------
// k3: masked-softmax + P@Wh via fp16 32x32x16 MFMA.
// Z_i computed on the (idle) MFMA pipe: acc2 = P @ ones — sums exactly the
// quantized+masked fp16 p used in the numerator (consistency preserved).
// cvt_pkrtz packs p pairs in 1 instr. Partials stored fp16 (halves traffic).
// Softmax shift = per-row upper bound M_i = lrelu(f1_i + max f2).
// ---------------------------------------------------------------------------
__global__ __launch_bounds__(256, 4) void k_attn(
    const unsigned long long* __restrict__ mb, const _Float16* __restrict__ wht,
    const float* __restrict__ f1, const float* __restrict__ f2,
    const float* __restrict__ f2mx,
    _Float16* __restrict__ accp, float* __restrict__ zp)
{
    __shared__ _Float16 whx[64 * 128];   // [h][j128], 8-elem groups XOR-swizzled
    const int t = threadIdx.x;
    const int w = t >> 6, lane = t & 63;
    const int bx = blockIdx.x;
    const int js = bx & 7;
    const int it = (bx >> 3) & 15;
    const int b = bx >> 7;
    const int I0 = it * 128 + w * 32;
    const int half = lane >> 5;
    const int m32 = lane & 31;
    const int row = I0 + m32;
    const int jb0 = js * 256;

    const float f1v = f1[b * NN + row];
    float Mi = f1v + f2mx[b];
    Mi = Mi > 0.f ? Mi : 0.2f * Mi;            // lrelu monotone -> valid bound
    const float LOG2E = 1.4426950408889634f;
    const float negMiL = -Mi * LOG2E;
    const float* f2p = f2 + b * NN;

    // this row's 4 mask words (j in [jb0, jb0+256))
    const unsigned long long* mrow = mb + (size_t)(b * NN + row) * 32 + js * 4;
    unsigned long long m[4];
    {
        ulonglong2 q0 = *(const ulonglong2*)mrow;
        ulonglong2 q1 = *(const ulonglong2*)(mrow + 2);
        m[0] = q0.x; m[1] = q0.y; m[2] = q1.x; m[3] = q1.y;
    }

    f16x8_t bones;
#pragma unroll
    for (int i = 0; i < 8; ++i) bones[i] = (_Float16)1.0f;

    f32x16_t acc0, acc1, acc2;
#pragma unroll
    for (int i = 0; i < 16; ++i) { acc0[i] = 0.f; acc1[i] = 0.f; acc2[i] = 0.f; }

#pragma unroll
    for (int stg = 0; stg < 2; ++stg) {
        const int jt = jb0 + stg * 128;
        if (stg) __syncthreads();
#pragma unroll
        for (int cc = 0; cc < 4; ++cc) {
            int c = t + cc * 256;
            int h = c >> 4, g = c & 15;
            int gp = g ^ (h & 15);
            size_t src = (size_t)(b * HID + h) * NN + jt + g * 8;
            *(uint4*)&whx[h * 128 + gp * 8] = *(const uint4*)&wht[src];
        }
        __syncthreads();
#pragma unroll
        for (int s8 = 0; s8 < 8; ++s8) {
            const int jl = jt + s8 * 16 + half * 8;   // this lane's 8-j group
            const uint32_t bits8 =
                (uint32_t)(m[stg * 2 + (s8 >> 2)] >> (((s8 & 3) * 16) + half * 8)) & 0xffu;
            float4 fa = *(const float4*)&f2p[jl];
            float4 fb = *(const float4*)&f2p[jl + 4];
            float fv[8] = {fa.x, fa.y, fa.z, fa.w, fb.x, fb.y, fb.z, fb.w};
            union { f16x2_t h2[4]; f16x8_t v; } ua;
#pragma unroll
            for (int jp = 0; jp < 4; ++jp) {
                float pv[2];
#pragma unroll
                for (int e = 0; e < 2; ++e) {
                    int jj = jp * 2 + e;
                    float t1 = f1v + fv[jj];
                    t1 = fmaxf(t1, 0.2f * t1);
                    pv[e] = (bits8 & (1u << jj))
                          ? __builtin_amdgcn_exp2f(fmaf(t1, LOG2E, negMiL))
                          : 0.f;
                }
                auto pk = __builtin_amdgcn_cvt_pkrtz(pv[0], pv[1]);  // __fp16x2
                ua.h2[jp] = *(f16x2_t*)&pk;                          // bit-pun
            }
            const int gx = (2 * s8 + half) ^ (m32 & 15);
            f16x8_t b0 = *(const f16x8_t*)&whx[m32 * 128 + (gx << 3)];
            f16x8_t b1 = *(const f16x8_t*)&whx[(m32 + 32) * 128 + (gx << 3)];
            acc0 = __builtin_amdgcn_mfma_f32_32x32x16_f16(ua.v, b0, acc0, 0, 0, 0);
            acc1 = __builtin_amdgcn_mfma_f32_32x32x16_f16(ua.v, b1, acc1, 0, 0, 0);
            acc2 = __builtin_amdgcn_mfma_f32_32x32x16_f16(ua.v, bones, acc2, 0, 0, 0);
        }
    }

    // epilogue: zp from acc2 (all columns equal; col-0 lanes write),
    // fp16 partials for the numerator.
    float* zb = zp + (size_t)(js * NB + b) * NN;
    _Float16* ap = accp + (size_t)(js * NB + b) * NN * HID;
#pragma unroll
    for (int r = 0; r < 16; ++r) {
        int rr = (r & 3) + 8 * (r >> 2) + 4 * half;   // verified C-layout (m74/m101)
        if (m32 == 0) zb[I0 + rr] = acc2[r];
        ap[(size_t)(I0 + rr) * HID + m32] = (_Float16)acc0[r];
        ap[(size_t)(I0 + rr) * HID + m32 + 32] = (_Float16)acc1[r];
    }
}

// ---------------------------------------------------------------------------
// k4: out = (sum_js acc_js) / (sum_js Z_js)   (fp16 partials, fp32 combine)
// ---------------------------------------------------------------------------
__global__ __launch_bounds__(256) void k_combine(
    const _Float16* __restrict__ accp, const float* __restrict__ zp,
    float* __restrict__ out)
{
    int gid = blockIdx.x * 256 + threadIdx.x;   // 0..262143 (4-h granules)
    int h4 = gid & 15;
    int rowg = gid >> 4;                        // b*N + n
    float z = 0.f;
    float s0 = 0.f, s1 = 0.f, s2 = 0.f, s3 = 0.f;
#pragma unroll
    for (int js = 0; js < JSPLIT; ++js) {
        size_t base = (size_t)js * NB * NN;
        z += zp[base + rowg];
        f16x4_t v = *(const f16x4_t*)&accp[(base + rowg) * HID + h4 * 4];
        s0 += (float)v[0]; s1 += (float)v[1]; s2 += (float)v[2]; s3 += (float)v[3];
    }
    float zi = 1.f / z;
    float4 o = {s0 * zi, s1 * zi, s2 * zi, s3 * zi};
    ((float4*)out)[gid] = o;
}

extern "C" void kernel_launch(void* const* d_in, const int* in_sizes, int n_in,
                              void* d_out, int out_size, void* d_ws, size_t ws_size,
                              hipStream_t stream)
{
    const float* x = (const float*)d_in[0];
    const int* adj = (const int*)d_in[1];
    const float* W = (const float*)d_in[2];
    const float* a = (const float*)d_in[3];
    float* out = (float*)d_out;
    char* ws = (char*)d_ws;

    _Float16* wht = (_Float16*)(ws);                              // 2 MB
    float* f1   = (float*)(ws + (2u << 20));                      // 64 KB
    float* f2   = (float*)(ws + (2u << 20) + (64u << 10));        // 64 KB
    float* f2mx = (float*)(ws + (2u << 20) + (128u << 10));       // 32 B
    unsigned long long* mbuf = (unsigned long long*)(ws + (3u << 20)); // 4 MB
    _Float16* accp = (_Float16*)(ws + (8u << 20));                // 16 MB
    float* zp   = (float*)(ws + (24u << 20));                     // 512 KB

    hipLaunchKernelGGL(k_prep, dim3(2304), dim3(256), 0, stream,
                       x, W, a, adj, mbuf, wht, f1, f2);
    hipLaunchKernelGGL(k_f2max, dim3(NB), dim3(256), 0, stream, f2, f2mx);
    hipLaunchKernelGGL(k_attn, dim3(1024), dim3(256), 0, stream, mbuf, wht, f1, f2, f2mx, accp, zp);
    hipLaunchKernelGGL(k_combine, dim3(1024), dim3(256), 0, stream, accp, zp, out);
}